// Round 1
// baseline (417.708 us; speedup 1.0000x reference)
//
#include <hip/hip_runtime.h>

// ---------------------------------------------------------------------------
// TransformerBlock on MI355X (gfx950): bf16 MFMA pipeline
//   B=4 S=2048 D=768 H=12 hs=64 F=3072, M=B*S=8192
// Stages:
//   castx: x fp32 -> bf16
//   tcast: weights fp32 [R][C] -> bf16 [C][R] (pre-transposed for GEMM B^T)
//   gemm : 128x128 tile, BK=32, 4 waves, global_load_lds(16), 16x16x32 MFMA
//   vtrans: v [B,S,H,hs] -> vT [B,H,hs,S]
//   attn : causal flash attention, QBLK=KBLK=64
// ---------------------------------------------------------------------------

typedef __attribute__((ext_vector_type(4))) float f32x4;
typedef __attribute__((ext_vector_type(8))) short bf16x8;   // 8 bf16 in 4 VGPRs
typedef __attribute__((ext_vector_type(4))) unsigned short u16x4;

#define GLB_AS __attribute__((address_space(1)))
#define LDS_AS __attribute__((address_space(3)))

__device__ __forceinline__ unsigned short f2bf(float f) {
  unsigned int u = __float_as_uint(f);
  u = (u + 0x7FFFu + ((u >> 16) & 1u)) >> 16;   // RNE
  return (unsigned short)u;
}

__device__ __forceinline__ void gload16(const void* g, void* l) {
  __builtin_amdgcn_global_load_lds((const GLB_AS unsigned int*)g,
                                   (LDS_AS unsigned int*)l, 16, 0, 0);
}

// ---------------------------------------------------------------- cast x ---
__global__ void castx(const float* __restrict__ in, unsigned short* __restrict__ out, int n) {
  int i = (blockIdx.x * 256 + threadIdx.x) * 4;
  if (i < n) {
    float4 f = *(const float4*)&in[i];
    u16x4 o;
    o[0] = f2bf(f.x); o[1] = f2bf(f.y); o[2] = f2bf(f.z); o[3] = f2bf(f.w);
    *(u16x4*)&out[i] = o;
  }
}

// ---------------------------------------------- weight transpose + cast ----
// in fp32 [R][C] (batch z, stride R*C) -> out bf16 [C][R] (stride R*C), *scale
__global__ void tcast(const float* __restrict__ in, unsigned short* __restrict__ out,
                      int R, int C, float scale) {
  __shared__ float tile[32][33];
  const float* inb = in + (size_t)blockIdx.z * R * C;
  unsigned short* outb = out + (size_t)blockIdx.z * R * C;
  int bx = blockIdx.x * 32;  // C dim
  int by = blockIdx.y * 32;  // R dim
  int tx = threadIdx.x, ty = threadIdx.y;
  #pragma unroll
  for (int i = 0; i < 32; i += 8) {
    int r = by + ty + i, c = bx + tx;
    if (r < R && c < C) tile[ty + i][tx] = inb[(size_t)r * C + c];
  }
  __syncthreads();
  #pragma unroll
  for (int i = 0; i < 32; i += 8) {
    int c = bx + ty + i, r = by + tx;
    if (r < R && c < C) outb[(size_t)c * R + r] = f2bf(tile[tx][ty + i] * scale);
  }
}

// ------------------------------------------------- v -> vT (bf16->bf16) ----
// v [B,S,H*hs] row-major; vT [B,H,hs,S]
__global__ void vtrans(const unsigned short* __restrict__ v, unsigned short* __restrict__ vT) {
  __shared__ unsigned short tile[32][33];
  int bh = blockIdx.z, b = bh / 12, h = bh % 12;
  int s0 = blockIdx.x * 32, e0 = blockIdx.y * 32;
  int tx = threadIdx.x, ty = threadIdx.y;
  #pragma unroll
  for (int i = 0; i < 32; i += 8)
    tile[ty + i][tx] = v[(size_t)(b * 2048 + s0 + ty + i) * 768 + h * 64 + e0 + tx];
  __syncthreads();
  #pragma unroll
  for (int i = 0; i < 32; i += 8)
    vT[(size_t)((b * 12 + h) * 64 + e0 + ty + i) * 2048 + s0 + tx] = tile[tx][ty + i];
}

// ------------------------------------------------------------------ GEMM ---
// C[M,N] = A[M,K] @ Bt[N,K]^T ; epilogue by EPI bits:
//   1 = +bias[col], 2 = relu, 4 = +resid[row*N+col] (fp32),
//   8 = store fp32 Cf, 16 = store bf16 Cb
template <int EPI>
__global__ void gemm_bf16(const unsigned short* __restrict__ A,
                          const unsigned short* __restrict__ Bt,
                          const float* __restrict__ bias,
                          const float* __restrict__ resid,
                          float* __restrict__ Cf,
                          unsigned short* __restrict__ Cb,
                          int M, int N, int K) {
  __shared__ unsigned short Alds[128 * 32];
  __shared__ unsigned short Blds[128 * 32];
  const int tid = threadIdx.x;
  const int lane = tid & 63;
  const int w = tid >> 6;
  const int wm = w & 1, wn = w >> 1;             // 2x2 wave grid
  const int bm = blockIdx.x * 128, bn = blockIdx.y * 128;

  f32x4 acc[4][4] = {};

  const int r0 = tid >> 2;            // staging row (issue 0)
  const int c0 = (tid & 3) * 8;       // staging col (elements)

  for (int k0 = 0; k0 < K; k0 += 32) {
    __syncthreads();
    #pragma unroll
    for (int i = 0; i < 2; ++i) {
      int row = r0 + i * 64;
      gload16(&A[(size_t)(bm + row) * K + k0 + c0], &Alds[row * 32 + c0]);
      gload16(&Bt[(size_t)(bn + row) * K + k0 + c0], &Blds[row * 32 + c0]);
    }
    __syncthreads();
    bf16x8 af[4], bf[4];
    #pragma unroll
    for (int m = 0; m < 4; ++m)
      af[m] = *(const bf16x8*)&Alds[(wm * 64 + m * 16 + (lane & 15)) * 32 + (lane >> 4) * 8];
    #pragma unroll
    for (int n = 0; n < 4; ++n)
      bf[n] = *(const bf16x8*)&Blds[(wn * 64 + n * 16 + (lane & 15)) * 32 + (lane >> 4) * 8];
    #pragma unroll
    for (int m = 0; m < 4; ++m)
      #pragma unroll
      for (int n = 0; n < 4; ++n)
        acc[m][n] = __builtin_amdgcn_mfma_f32_16x16x32_bf16(af[m], bf[n], acc[m][n], 0, 0, 0);
  }

  const int crow0 = bm + wm * 64 + (lane >> 4) * 4;
  const int ccol0 = bn + wn * 64 + (lane & 15);
  #pragma unroll
  for (int m = 0; m < 4; ++m) {
    #pragma unroll
    for (int n = 0; n < 4; ++n) {
      int col = ccol0 + n * 16;
      #pragma unroll
      for (int r = 0; r < 4; ++r) {
        int row = crow0 + m * 16 + r;
        float v = acc[m][n][r];
        if constexpr (EPI & 1) v += bias[col];
        if constexpr (EPI & 4) v += resid[(size_t)row * N + col];
        if constexpr (EPI & 2) v = fmaxf(v, 0.f);
        if constexpr (EPI & 8) Cf[(size_t)row * N + col] = v;
        if constexpr (EPI & 16) Cb[(size_t)row * N + col] = f2bf(v);
      }
    }
  }
}

// ------------------------------------------------------------- attention ---
// grid.x = S/64 (q block), grid.y = B*H. 4 waves, each owns 16 q rows.
// q,k: [B,S,H*hs] bf16 (q pre-scaled by 1/8 via WqT). vT: [B,H,hs,S] bf16.
// z out: [B,S,H*hs] bf16.
__global__ void attn_fwd(const unsigned short* __restrict__ q,
                         const unsigned short* __restrict__ k,
                         const unsigned short* __restrict__ vT,
                         unsigned short* __restrict__ z) {
  __shared__ unsigned short Klds[2 * 64 * 32];  // [hs-plane][kv row][32]
  __shared__ unsigned short Vlds[2 * 64 * 32];  // [kv-plane][e row][32]
  __shared__ unsigned short Plds[4 * 2 * 16 * 32]; // per-wave [kv-plane][qrow][32]
  const int qb = blockIdx.x;
  const int bh = blockIdx.y;
  const int b = bh / 12, h = bh % 12;
  const int tid = threadIdx.x, lane = tid & 63, w = tid >> 6;
  const int q0 = qb * 64;

  // Q fragments, held in registers for the whole block
  const int qrow = q0 + w * 16 + (lane & 15);
  const size_t qoff = (size_t)(b * 2048 + qrow) * 768 + h * 64 + (lane >> 4) * 8;
  bf16x8 qf0 = *(const bf16x8*)&q[qoff];
  bf16x8 qf1 = *(const bf16x8*)&q[qoff + 32];

  f32x4 accO[4] = {};
  float mrow[4], lrow[4];
  #pragma unroll
  for (int i = 0; i < 4; ++i) { mrow[i] = -3.0e38f; lrow[i] = 0.f; }

  const int srow = tid >> 2;
  const int scol = (tid & 3) * 8;
  const size_t kbase = (size_t)(b * 2048) * 768 + h * 64;
  const size_t vbase = (size_t)((b * 12 + h) * 64) * 2048;

  for (int t = 0; t <= qb; ++t) {
    const int kv0 = t * 64;
    __syncthreads();
    #pragma unroll
    for (int i = 0; i < 2; ++i) {
      gload16(&k[kbase + (size_t)(kv0 + srow) * 768 + i * 32 + scol],
              &Klds[i * 2048 + srow * 32 + scol]);
      gload16(&vT[vbase + (size_t)srow * 2048 + kv0 + i * 32 + scol],
              &Vlds[i * 2048 + srow * 32 + scol]);
    }
    __syncthreads();

    // S = Q K^T (pre-scaled)
    f32x4 s[4];
    #pragma unroll
    for (int n = 0; n < 4; ++n) {
      bf16x8 kf0 = *(const bf16x8*)&Klds[0 * 2048 + (n * 16 + (lane & 15)) * 32 + (lane >> 4) * 8];
      bf16x8 kf1 = *(const bf16x8*)&Klds[1 * 2048 + (n * 16 + (lane & 15)) * 32 + (lane >> 4) * 8];
      f32x4 acc0 = {};
      acc0 = __builtin_amdgcn_mfma_f32_16x16x32_bf16(qf0, kf0, acc0, 0, 0, 0);
      s[n] = __builtin_amdgcn_mfma_f32_16x16x32_bf16(qf1, kf1, acc0, 0, 0, 0);
    }

    if (t == qb) {  // causal mask on the diagonal tile
      #pragma unroll
      for (int n = 0; n < 4; ++n) {
        int col = kv0 + n * 16 + (lane & 15);
        #pragma unroll
        for (int r = 0; r < 4; ++r) {
          int rowg = q0 + w * 16 + (lane >> 4) * 4 + r;
          if (col > rowg) s[n][r] = -3.0e38f;
        }
      }
    }

    // online softmax (row stats across 16 lanes of each quarter-wave)
    float pmax[4];
    #pragma unroll
    for (int r = 0; r < 4; ++r)
      pmax[r] = fmaxf(fmaxf(s[0][r], s[1][r]), fmaxf(s[2][r], s[3][r]));
    #pragma unroll
    for (int off = 1; off < 16; off <<= 1)
      #pragma unroll
      for (int r = 0; r < 4; ++r) pmax[r] = fmaxf(pmax[r], __shfl_xor(pmax[r], off));

    float p[4][4];  // [n][r]
    float rs[4];
    #pragma unroll
    for (int r = 0; r < 4; ++r) {
      float mnew = fmaxf(mrow[r], pmax[r]);
      float sc = __expf(mrow[r] - mnew);
      mrow[r] = mnew;
      float sum = 0.f;
      #pragma unroll
      for (int n = 0; n < 4; ++n) { p[n][r] = __expf(s[n][r] - mnew); sum += p[n][r]; }
      rs[r] = sum;
      lrow[r] *= sc;
      #pragma unroll
      for (int n = 0; n < 4; ++n) accO[n][r] *= sc;
    }
    #pragma unroll
    for (int off = 1; off < 16; off <<= 1)
      #pragma unroll
      for (int r = 0; r < 4; ++r) rs[r] += __shfl_xor(rs[r], off);
    #pragma unroll
    for (int r = 0; r < 4; ++r) lrow[r] += rs[r];

    // P -> LDS (bf16), per-wave region, [kv-plane][qrow][32] layout
    #pragma unroll
    for (int n = 0; n < 4; ++n)
      #pragma unroll
      for (int r = 0; r < 4; ++r)
        Plds[w * 1024 + (n >> 1) * 512 + ((lane >> 4) * 4 + r) * 32 + (n & 1) * 16 + (lane & 15)]
            = f2bf(p[n][r]);
    __syncthreads();

    // O += P V
    #pragma unroll
    for (int kk = 0; kk < 2; ++kk) {
      bf16x8 pf = *(const bf16x8*)&Plds[w * 1024 + kk * 512 + (lane & 15) * 32 + (lane >> 4) * 8];
      #pragma unroll
      for (int n = 0; n < 4; ++n) {
        bf16x8 vf = *(const bf16x8*)&Vlds[kk * 2048 + (n * 16 + (lane & 15)) * 32 + (lane >> 4) * 8];
        accO[n] = __builtin_amdgcn_mfma_f32_16x16x32_bf16(pf, vf, accO[n], 0, 0, 0);
      }
    }
  }

  #pragma unroll
  for (int n = 0; n < 4; ++n)
    #pragma unroll
    for (int r = 0; r < 4; ++r) {
      int rowg = q0 + w * 16 + (lane >> 4) * 4 + r;
      z[(size_t)(b * 2048 + rowg) * 768 + h * 64 + n * 16 + (lane & 15)]
          = f2bf(accO[n][r] / lrow[r]);
    }
}

// ---------------------------------------------------------------- launch ---
extern "C" void kernel_launch(void* const* d_in, const int* in_sizes, int n_in,
                              void* d_out, int out_size, void* d_ws, size_t ws_size,
                              hipStream_t stream) {
  const float* x  = (const float*)d_in[0];
  const float* Wq = (const float*)d_in[1];
  const float* Wk = (const float*)d_in[2];
  const float* Wv = (const float*)d_in[3];
  const float* Wo = (const float*)d_in[4];
  const float* bo = (const float*)d_in[5];
  const float* W1 = (const float*)d_in[6];
  const float* b1 = (const float*)d_in[7];
  const float* W2 = (const float*)d_in[8];
  const float* b2 = (const float*)d_in[9];
  float* out = (float*)d_out;

  const int B = 4, S = 2048, D = 768, H = 12, hs = 64, F = 3072;
  const int M = B * S;                 // 8192
  const size_t MD = (size_t)M * D;     // 6291456

  // workspace layout (bytes): h reuses xb..vb (4*MD shorts == M*F shorts)
  unsigned short* xb   = (unsigned short*)d_ws;
  unsigned short* qb   = xb + MD;
  unsigned short* kb   = qb + MD;
  unsigned short* vb   = kb + MD;
  unsigned short* hbuf = xb;           // [M, F] bf16, reuse
  unsigned short* vT   = vb + MD;
  unsigned short* zb   = vT + MD;
  float*          z2f  = (float*)(zb + MD);
  unsigned short* z2b  = (unsigned short*)(z2f + MD);
  unsigned short* wqT  = z2b + MD;
  unsigned short* wkT  = wqT + (size_t)D * D;
  unsigned short* wvT  = wkT + (size_t)D * D;
  unsigned short* woT  = wvT + (size_t)D * D;
  unsigned short* w1T  = woT + (size_t)D * D;
  unsigned short* w2T  = w1T + (size_t)D * F;

  dim3 tb(32, 8);

  castx<<<dim3((int)(MD / 4 / 256)), 256, 0, stream>>>(x, xb, (int)MD);

  // weights: [R][C] -> [C][R]; Wq gets the 1/sqrt(hs)=0.125 scale (exact)
  tcast<<<dim3(hs / 32, D / 32, H), tb, 0, stream>>>(Wq, wqT, D, hs, 0.125f);
  tcast<<<dim3(hs / 32, D / 32, H), tb, 0, stream>>>(Wk, wkT, D, hs, 1.0f);
  tcast<<<dim3(hs / 32, D / 32, H), tb, 0, stream>>>(Wv, wvT, D, hs, 1.0f);
  tcast<<<dim3(D / 32, D / 32, 1), tb, 0, stream>>>(Wo, woT, D, D, 1.0f);
  tcast<<<dim3(F / 32, D / 32, 1), tb, 0, stream>>>(W1, w1T, D, F, 1.0f);
  tcast<<<dim3(D / 32, F / 32, 1), tb, 0, stream>>>(W2, w2T, F, D, 1.0f);

  // QKV projections: [M,D] @ [D,D] -> bf16
  gemm_bf16<16><<<dim3(M / 128, D / 128), 256, 0, stream>>>(xb, wqT, nullptr, nullptr, nullptr, qb, M, D, D);
  gemm_bf16<16><<<dim3(M / 128, D / 128), 256, 0, stream>>>(xb, wkT, nullptr, nullptr, nullptr, kb, M, D, D);
  gemm_bf16<16><<<dim3(M / 128, D / 128), 256, 0, stream>>>(xb, wvT, nullptr, nullptr, nullptr, vb, M, D, D);

  vtrans<<<dim3(S / 32, hs / 32, B * H), tb, 0, stream>>>(vb, vT);

  attn_fwd<<<dim3(S / 64, B * H), 256, 0, stream>>>(qb, kb, vT, zb);

  // z @ Wo + bo + x -> z2 (fp32 + bf16)
  gemm_bf16<1 | 4 | 8 | 16><<<dim3(M / 128, D / 128), 256, 0, stream>>>(zb, woT, bo, x, z2f, z2b, M, D, D);

  // relu(z2 @ W1 + b1) -> h (bf16)
  gemm_bf16<1 | 2 | 16><<<dim3(M / 128, F / 128), 256, 0, stream>>>(z2b, w1T, b1, nullptr, nullptr, hbuf, M, F, D);

  // h @ W2 + b2 + z2 -> out (fp32)
  gemm_bf16<1 | 4 | 8><<<dim3(M / 128, D / 128), 256, 0, stream>>>(hbuf, w2T, b2, z2f, out, nullptr, M, D, F);
}

// Round 2
// 348.356 us; speedup vs baseline: 1.1991x; 1.1991x over previous
//
#include <hip/hip_runtime.h>

// ---------------------------------------------------------------------------
// TransformerBlock on MI355X (gfx950): bf16 MFMA pipeline
//   B=4 S=2048 D=768 H=12 hs=64 F=3072, M=B*S=8192
// Round 2: attention rebalanced (paired causal q-blocks, K/V double-buffer,
//          1 barrier/tile), fused QKV GEMM, XCD-swizzled GEMM grids.
// ---------------------------------------------------------------------------

typedef __attribute__((ext_vector_type(4))) float f32x4;
typedef __attribute__((ext_vector_type(8))) short bf16x8;   // 8 bf16 in 4 VGPRs
typedef __attribute__((ext_vector_type(4))) unsigned short u16x4;

#define GLB_AS __attribute__((address_space(1)))
#define LDS_AS __attribute__((address_space(3)))

__device__ __forceinline__ unsigned short f2bf(float f) {
  unsigned int u = __float_as_uint(f);
  u = (u + 0x7FFFu + ((u >> 16) & 1u)) >> 16;   // RNE
  return (unsigned short)u;
}

__device__ __forceinline__ void gload16(const void* g, void* l) {
  __builtin_amdgcn_global_load_lds((const GLB_AS unsigned int*)g,
                                   (LDS_AS unsigned int*)l, 16, 0, 0);
}

// bijective XCD swizzle (m204): contiguous chunk of wg-ids per XCD
__device__ __forceinline__ int xcd_swz(int orig, int nwg) {
  int q = nwg >> 3, r = nwg & 7;
  int xcd = orig & 7, rest = orig >> 3;
  return (xcd < r ? xcd * (q + 1) : r * (q + 1) + (xcd - r) * q) + rest;
}

// ---------------------------------------------------------------- cast x ---
__global__ void castx(const float* __restrict__ in, unsigned short* __restrict__ out, int n) {
  int i = (blockIdx.x * 256 + threadIdx.x) * 4;
  if (i < n) {
    float4 f = *(const float4*)&in[i];
    u16x4 o;
    o[0] = f2bf(f.x); o[1] = f2bf(f.y); o[2] = f2bf(f.z); o[3] = f2bf(f.w);
    *(u16x4*)&out[i] = o;
  }
}

// ---------------------------------------------- weight transpose + cast ----
__global__ void tcast(const float* __restrict__ in, unsigned short* __restrict__ out,
                      int R, int C, float scale) {
  __shared__ float tile[32][33];
  const float* inb = in + (size_t)blockIdx.z * R * C;
  unsigned short* outb = out + (size_t)blockIdx.z * R * C;
  int bx = blockIdx.x * 32;  // C dim
  int by = blockIdx.y * 32;  // R dim
  int tx = threadIdx.x, ty = threadIdx.y;
  #pragma unroll
  for (int i = 0; i < 32; i += 8) {
    int r = by + ty + i, c = bx + tx;
    if (r < R && c < C) tile[ty + i][tx] = inb[(size_t)r * C + c];
  }
  __syncthreads();
  #pragma unroll
  for (int i = 0; i < 32; i += 8) {
    int c = bx + ty + i, r = by + tx;
    if (r < R && c < C) outb[(size_t)c * R + r] = f2bf(tile[tx][ty + i] * scale);
  }
}

// ------------------------------------------------- v -> vT (bf16->bf16) ----
__global__ void vtrans(const unsigned short* __restrict__ v, unsigned short* __restrict__ vT) {
  __shared__ unsigned short tile[32][33];
  int bh = blockIdx.z, b = bh / 12, h = bh % 12;
  int s0 = blockIdx.x * 32, e0 = blockIdx.y * 32;
  int tx = threadIdx.x, ty = threadIdx.y;
  #pragma unroll
  for (int i = 0; i < 32; i += 8)
    tile[ty + i][tx] = v[(size_t)(b * 2048 + s0 + ty + i) * 768 + h * 64 + e0 + tx];
  __syncthreads();
  #pragma unroll
  for (int i = 0; i < 32; i += 8)
    vT[(size_t)((b * 12 + h) * 64 + e0 + ty + i) * 2048 + s0 + tx] = tile[tx][ty + i];
}

// ------------------------------------------------------------------ GEMM ---
// C[M,N] = A[M,K] @ Bt[N,K]^T ; epilogue by EPI bits:
//   1 = +bias[col], 2 = relu, 4 = +resid (fp32), 8 = store fp32 Cf,
//   16 = store bf16 Cb, 32 = QKV split bf16 store (cols [0,768) -> Cb,
//        [768,1536) -> Cb+segN, [1536,2304) -> Cb+2*segN; row stride 768)
template <int EPI>
__global__ void gemm_bf16(const unsigned short* __restrict__ A,
                          const unsigned short* __restrict__ Bt,
                          const float* __restrict__ bias,
                          const float* __restrict__ resid,
                          float* __restrict__ Cf,
                          unsigned short* __restrict__ Cb,
                          int M, int N, int K, int gx, size_t segN) {
  __shared__ unsigned short Alds[128 * 32];
  __shared__ unsigned short Blds[128 * 32];
  const int tid = threadIdx.x;
  const int lane = tid & 63;
  const int w = tid >> 6;
  const int wm = w & 1, wn = w >> 1;             // 2x2 wave grid
  const int wg = xcd_swz(blockIdx.x, gridDim.x);
  const int bm = (wg % gx) * 128, bn = (wg / gx) * 128;

  f32x4 acc[4][4] = {};

  const int r0 = tid >> 2;            // staging row
  const int c0 = (tid & 3) * 8;       // staging col (elements)

  for (int k0 = 0; k0 < K; k0 += 32) {
    __syncthreads();
    #pragma unroll
    for (int i = 0; i < 2; ++i) {
      int row = r0 + i * 64;
      gload16(&A[(size_t)(bm + row) * K + k0 + c0], &Alds[row * 32 + c0]);
      gload16(&Bt[(size_t)(bn + row) * K + k0 + c0], &Blds[row * 32 + c0]);
    }
    __syncthreads();
    bf16x8 af[4], bf[4];
    #pragma unroll
    for (int m = 0; m < 4; ++m)
      af[m] = *(const bf16x8*)&Alds[(wm * 64 + m * 16 + (lane & 15)) * 32 + (lane >> 4) * 8];
    #pragma unroll
    for (int n = 0; n < 4; ++n)
      bf[n] = *(const bf16x8*)&Blds[(wn * 64 + n * 16 + (lane & 15)) * 32 + (lane >> 4) * 8];
    #pragma unroll
    for (int m = 0; m < 4; ++m)
      #pragma unroll
      for (int n = 0; n < 4; ++n)
        acc[m][n] = __builtin_amdgcn_mfma_f32_16x16x32_bf16(af[m], bf[n], acc[m][n], 0, 0, 0);
  }

  const int crow0 = bm + wm * 64 + (lane >> 4) * 4;
  const int ccol0 = bn + wn * 64 + (lane & 15);
  const int seg = bn / 768;                         // block-constant (768%128==0)
  const int lcol0 = (bn % 768) + wn * 64 + (lane & 15);
  #pragma unroll
  for (int m = 0; m < 4; ++m) {
    #pragma unroll
    for (int n = 0; n < 4; ++n) {
      int col = ccol0 + n * 16;
      #pragma unroll
      for (int r = 0; r < 4; ++r) {
        int row = crow0 + m * 16 + r;
        float v = acc[m][n][r];
        if constexpr (EPI & 1) v += bias[col];
        if constexpr (EPI & 4) v += resid[(size_t)row * N + col];
        if constexpr (EPI & 2) v = fmaxf(v, 0.f);
        if constexpr (EPI & 8) Cf[(size_t)row * N + col] = v;
        if constexpr (EPI & 16) Cb[(size_t)row * N + col] = f2bf(v);
        if constexpr (EPI & 32)
          Cb[(size_t)seg * segN + (size_t)row * 768 + lcol0 + n * 16] = f2bf(v);
      }
    }
  }
}

// ------------------------------------------------------------- attention ---
// Paired causal flash attention. grid.x = (S/64/2) * B*H flattened (768),
// XCD-chunk swizzled. Each block does q-blocks {pi, 31-pi}: 33 tiles total.
// 4 waves x 16 q-rows; KVBLK=64; K/V double-buffered; 1 barrier per tile.
__global__ void attn_fwd(const unsigned short* __restrict__ q,
                         const unsigned short* __restrict__ k,
                         const unsigned short* __restrict__ vT,
                         unsigned short* __restrict__ z) {
  __shared__ unsigned short Klds[2 * 2 * 64 * 32];  // [buf][hs-plane][kv row][32]
  __shared__ unsigned short Vlds[2 * 2 * 64 * 32];  // [buf][kv-plane][e row][32]
  __shared__ unsigned short Plds[4 * 2 * 16 * 32];  // per-wave [kv-plane][qrow][32]

  const int wgid = xcd_swz(blockIdx.x, gridDim.x);  // 768 blocks
  const int pi = wgid & 15;         // pair index 0..15
  const int bh = wgid >> 4;         // 0..47
  const int b = bh / 12, h = bh % 12;
  const int tid = threadIdx.x, lane = tid & 63, w = tid >> 6;
  const int srow = tid >> 2;
  const int scol = (tid & 3) * 8;
  const size_t kbase = (size_t)(b * 2048) * 768 + h * 64;
  const size_t vbase = (size_t)((b * 12 + h) * 64) * 2048;

  #pragma unroll 1
  for (int seg = 0; seg < 2; ++seg) {
    const int qb = seg == 0 ? pi : 31 - pi;
    const int q0 = qb * 64;
    const int nt = qb + 1;

    // Q fragments in registers for this segment (q pre-scaled by 1/8)
    const int qrow = q0 + w * 16 + (lane & 15);
    const size_t qoff = (size_t)(b * 2048 + qrow) * 768 + h * 64 + (lane >> 4) * 8;
    bf16x8 qf0 = *(const bf16x8*)&q[qoff];
    bf16x8 qf1 = *(const bf16x8*)&q[qoff + 32];

    f32x4 accO[4] = {};
    float mrow[4], lrow[4];
    #pragma unroll
    for (int i = 0; i < 4; ++i) { mrow[i] = -3.0e38f; lrow[i] = 0.f; }

    // prologue: stage tile 0 into buf 0
    {
      const int kv0 = 0;
      #pragma unroll
      for (int i = 0; i < 2; ++i) {
        gload16(&k[kbase + (size_t)(kv0 + srow) * 768 + i * 32 + scol],
                &Klds[i * 2048 + srow * 32 + scol]);
        gload16(&vT[vbase + (size_t)srow * 2048 + kv0 + i * 32 + scol],
                &Vlds[i * 2048 + srow * 32 + scol]);
      }
    }
    __syncthreads();

    int buf = 0;
    for (int t = 0; t < nt; ++t) {
      // issue next tile's stage into buf^1 (overlaps with compute below)
      if (t + 1 < nt) {
        const int kv1 = (t + 1) * 64;
        const int bo = (buf ^ 1) * 4096;
        #pragma unroll
        for (int i = 0; i < 2; ++i) {
          gload16(&k[kbase + (size_t)(kv1 + srow) * 768 + i * 32 + scol],
                  &Klds[bo + i * 2048 + srow * 32 + scol]);
          gload16(&vT[vbase + (size_t)srow * 2048 + kv1 + i * 32 + scol],
                  &Vlds[bo + i * 2048 + srow * 32 + scol]);
        }
      }

      const int kv0 = t * 64;
      const int kb_ = buf * 4096;

      // S = Q K^T (pre-scaled)
      f32x4 s[4];
      #pragma unroll
      for (int n = 0; n < 4; ++n) {
        bf16x8 kf0 = *(const bf16x8*)&Klds[kb_ + 0 * 2048 + (n * 16 + (lane & 15)) * 32 + (lane >> 4) * 8];
        bf16x8 kf1 = *(const bf16x8*)&Klds[kb_ + 1 * 2048 + (n * 16 + (lane & 15)) * 32 + (lane >> 4) * 8];
        f32x4 acc0 = {};
        acc0 = __builtin_amdgcn_mfma_f32_16x16x32_bf16(qf0, kf0, acc0, 0, 0, 0);
        s[n] = __builtin_amdgcn_mfma_f32_16x16x32_bf16(qf1, kf1, acc0, 0, 0, 0);
      }

      if (t == nt - 1) {  // diagonal tile: causal mask
        #pragma unroll
        for (int n = 0; n < 4; ++n) {
          int col = kv0 + n * 16 + (lane & 15);
          #pragma unroll
          for (int r = 0; r < 4; ++r) {
            int rowg = q0 + w * 16 + (lane >> 4) * 4 + r;
            if (col > rowg) s[n][r] = -3.0e38f;
          }
        }
      }

      // online softmax (rows live across 16 lanes)
      float pmax[4];
      #pragma unroll
      for (int r = 0; r < 4; ++r)
        pmax[r] = fmaxf(fmaxf(s[0][r], s[1][r]), fmaxf(s[2][r], s[3][r]));
      #pragma unroll
      for (int off = 1; off < 16; off <<= 1)
        #pragma unroll
        for (int r = 0; r < 4; ++r) pmax[r] = fmaxf(pmax[r], __shfl_xor(pmax[r], off));

      float p[4][4];
      float rs[4];
      #pragma unroll
      for (int r = 0; r < 4; ++r) {
        float mnew = fmaxf(mrow[r], pmax[r]);
        float sc = __expf(mrow[r] - mnew);
        mrow[r] = mnew;
        float sum = 0.f;
        #pragma unroll
        for (int n = 0; n < 4; ++n) { p[n][r] = __expf(s[n][r] - mnew); sum += p[n][r]; }
        rs[r] = sum;
        lrow[r] *= sc;
        #pragma unroll
        for (int n = 0; n < 4; ++n) accO[n][r] *= sc;
      }
      #pragma unroll
      for (int off = 1; off < 16; off <<= 1)
        #pragma unroll
        for (int r = 0; r < 4; ++r) rs[r] += __shfl_xor(rs[r], off);
      #pragma unroll
      for (int r = 0; r < 4; ++r) lrow[r] += rs[r];

      // P -> LDS (wave-private region; no barrier needed)
      #pragma unroll
      for (int n = 0; n < 4; ++n)
        #pragma unroll
        for (int r = 0; r < 4; ++r)
          Plds[w * 1024 + (n >> 1) * 512 + ((lane >> 4) * 4 + r) * 32 + (n & 1) * 16 + (lane & 15)]
              = f2bf(p[n][r]);

      // O += P V
      #pragma unroll
      for (int kk = 0; kk < 2; ++kk) {
        bf16x8 pf = *(const bf16x8*)&Plds[w * 1024 + kk * 512 + (lane & 15) * 32 + (lane >> 4) * 8];
        #pragma unroll
        for (int n = 0; n < 4; ++n) {
          bf16x8 vf = *(const bf16x8*)&Vlds[kb_ + kk * 2048 + (n * 16 + (lane & 15)) * 32 + (lane >> 4) * 8];
          accO[n] = __builtin_amdgcn_mfma_f32_16x16x32_bf16(pf, vf, accO[n], 0, 0, 0);
        }
      }

      __syncthreads();   // drains stage of t+1 (vmcnt) + protects buf reuse
      buf ^= 1;
    }

    #pragma unroll
    for (int n = 0; n < 4; ++n)
      #pragma unroll
      for (int r = 0; r < 4; ++r) {
        int rowg = q0 + w * 16 + (lane >> 4) * 4 + r;
        z[(size_t)(b * 2048 + rowg) * 768 + h * 64 + n * 16 + (lane & 15)]
            = f2bf(accO[n][r] / lrow[r]);
      }
  }
}

// ---------------------------------------------------------------- launch ---
extern "C" void kernel_launch(void* const* d_in, const int* in_sizes, int n_in,
                              void* d_out, int out_size, void* d_ws, size_t ws_size,
                              hipStream_t stream) {
  const float* x  = (const float*)d_in[0];
  const float* Wq = (const float*)d_in[1];
  const float* Wk = (const float*)d_in[2];
  const float* Wv = (const float*)d_in[3];
  const float* Wo = (const float*)d_in[4];
  const float* bo = (const float*)d_in[5];
  const float* W1 = (const float*)d_in[6];
  const float* b1 = (const float*)d_in[7];
  const float* W2 = (const float*)d_in[8];
  const float* b2 = (const float*)d_in[9];
  float* out = (float*)d_out;

  const int B = 4, S = 2048, D = 768, H = 12, hs = 64, F = 3072;
  const int M = B * S;                 // 8192
  const size_t MD = (size_t)M * D;     // 6291456

  unsigned short* xb   = (unsigned short*)d_ws;
  unsigned short* qb   = xb + MD;
  unsigned short* kb   = qb + MD;      // contiguous with qb
  unsigned short* vb   = kb + MD;      // contiguous with kb
  unsigned short* hbuf = xb;           // [M, F] bf16, reuse
  unsigned short* vT   = vb + MD;
  unsigned short* zb   = vT + MD;
  float*          z2f  = (float*)(zb + MD);
  unsigned short* z2b  = (unsigned short*)(z2f + MD);
  unsigned short* wqkvT= z2b + MD;     // [2304][768] bf16 (q rows, k rows, v rows)
  unsigned short* woT  = wqkvT + 3 * (size_t)D * D;
  unsigned short* w1T  = woT + (size_t)D * D;
  unsigned short* w2T  = w1T + (size_t)D * F;

  dim3 tb(32, 8);

  castx<<<dim3((int)(MD / 4 / 256)), 256, 0, stream>>>(x, xb, (int)MD);

  // weights -> bf16, transposed; Wq gets the 1/sqrt(64)=0.125 scale (exact)
  tcast<<<dim3(hs / 32, D / 32, H), tb, 0, stream>>>(Wq, wqkvT, D, hs, 0.125f);
  tcast<<<dim3(hs / 32, D / 32, H), tb, 0, stream>>>(Wk, wqkvT + (size_t)D * D, D, hs, 1.0f);
  tcast<<<dim3(hs / 32, D / 32, H), tb, 0, stream>>>(Wv, wqkvT + 2 * (size_t)D * D, D, hs, 1.0f);
  tcast<<<dim3(D / 32, D / 32, 1), tb, 0, stream>>>(Wo, woT, D, D, 1.0f);
  tcast<<<dim3(F / 32, D / 32, 1), tb, 0, stream>>>(W1, w1T, D, F, 1.0f);
  tcast<<<dim3(D / 32, F / 32, 1), tb, 0, stream>>>(W2, w2T, F, D, 1.0f);

  // fused QKV: [M,768] @ [768,2304] -> q,k,v bf16 (split store)
  {
    int gx = M / 128, gy = 3 * D / 128;  // 64 x 18
    gemm_bf16<32><<<dim3(gx * gy), 256, 0, stream>>>(xb, wqkvT, nullptr, nullptr,
                                                     nullptr, qb, M, 3 * D, D, gx, MD);
  }

  vtrans<<<dim3(S / 32, hs / 32, B * H), tb, 0, stream>>>(vb, vT);

  attn_fwd<<<dim3((S / 128) * B * H), 256, 0, stream>>>(qb, kb, vT, zb);

  // z @ Wo + bo + x -> z2 (fp32 + bf16)
  {
    int gx = M / 128, gy = D / 128;
    gemm_bf16<1 | 4 | 8 | 16><<<dim3(gx * gy), 256, 0, stream>>>(zb, woT, bo, x,
                                                                 z2f, z2b, M, D, D, gx, 0);
  }
  // relu(z2 @ W1 + b1) -> h (bf16)
  {
    int gx = M / 128, gy = F / 128;
    gemm_bf16<1 | 2 | 16><<<dim3(gx * gy), 256, 0, stream>>>(z2b, w1T, b1, nullptr,
                                                             nullptr, hbuf, M, F, D, gx, 0);
  }
  // h @ W2 + b2 + z2 -> out (fp32)
  {
    int gx = M / 128, gy = D / 128;
    gemm_bf16<1 | 4 | 8><<<dim3(gx * gy), 256, 0, stream>>>(hbuf, w2T, b2, z2f,
                                                            out, nullptr, M, D, F, gx, 0);
  }
}

// Round 3
// 308.454 us; speedup vs baseline: 1.3542x; 1.1294x over previous
//
#include <hip/hip_runtime.h>

// ---------------------------------------------------------------------------
// TransformerBlock on MI355X (gfx950): bf16 MFMA pipeline
//   B=4 S=2048 D=768 H=12 hs=64 F=3072, M=B*S=8192
// Round 3: swapped-QK^T attention (lane-local softmax, cvt_pk P-pack,
//          padded P LDS, K/V chunk-XOR swizzle, defer-max, exp2 domain).
// ---------------------------------------------------------------------------

typedef __attribute__((ext_vector_type(4))) float f32x4;
typedef __attribute__((ext_vector_type(8))) short bf16x8;   // 8 bf16 in 4 VGPRs
typedef __attribute__((ext_vector_type(4))) unsigned short u16x4;

#define GLB_AS __attribute__((address_space(1)))
#define LDS_AS __attribute__((address_space(3)))

__device__ __forceinline__ unsigned short f2bf(float f) {
  unsigned int u = __float_as_uint(f);
  u = (u + 0x7FFFu + ((u >> 16) & 1u)) >> 16;   // RNE
  return (unsigned short)u;
}

__device__ __forceinline__ void gload16(const void* g, void* l) {
  __builtin_amdgcn_global_load_lds((const GLB_AS unsigned int*)g,
                                   (LDS_AS unsigned int*)l, 16, 0, 0);
}

// bijective XCD swizzle (m204): contiguous chunk of wg-ids per XCD
__device__ __forceinline__ int xcd_swz(int orig, int nwg) {
  int q = nwg >> 3, r = nwg & 7;
  int xcd = orig & 7, rest = orig >> 3;
  return (xcd < r ? xcd * (q + 1) : r * (q + 1) + (xcd - r) * q) + rest;
}

// ---------------------------------------------------------------- cast x ---
__global__ void castx(const float* __restrict__ in, unsigned short* __restrict__ out, int n) {
  int i = (blockIdx.x * 256 + threadIdx.x) * 4;
  if (i < n) {
    float4 f = *(const float4*)&in[i];
    u16x4 o;
    o[0] = f2bf(f.x); o[1] = f2bf(f.y); o[2] = f2bf(f.z); o[3] = f2bf(f.w);
    *(u16x4*)&out[i] = o;
  }
}

// ---------------------------------------------- weight transpose + cast ----
__global__ void tcast(const float* __restrict__ in, unsigned short* __restrict__ out,
                      int R, int C, float scale) {
  __shared__ float tile[32][33];
  const float* inb = in + (size_t)blockIdx.z * R * C;
  unsigned short* outb = out + (size_t)blockIdx.z * R * C;
  int bx = blockIdx.x * 32;  // C dim
  int by = blockIdx.y * 32;  // R dim
  int tx = threadIdx.x, ty = threadIdx.y;
  #pragma unroll
  for (int i = 0; i < 32; i += 8) {
    int r = by + ty + i, c = bx + tx;
    tile[ty + i][tx] = inb[(size_t)r * C + c];
  }
  __syncthreads();
  #pragma unroll
  for (int i = 0; i < 32; i += 8) {
    int c = bx + ty + i, r = by + tx;
    outb[(size_t)c * R + r] = f2bf(tile[tx][ty + i] * scale);
  }
}

// Wq/Wk/Wv transposes in one launch: z in [0,36), w=z/12 picks the matrix.
__global__ void tcast3(const float* __restrict__ Wq, const float* __restrict__ Wk,
                       const float* __restrict__ Wv, unsigned short* __restrict__ out,
                       float qscale) {
  __shared__ float tile[32][33];
  const int R = 768, C = 64;
  int z = blockIdx.z, wsel = z / 12, head = z % 12;
  const float* in = (wsel == 0 ? Wq : wsel == 1 ? Wk : Wv) + (size_t)head * R * C;
  unsigned short* outb = out + (size_t)wsel * R * R + (size_t)head * R * C;
  float scale = wsel == 0 ? qscale : 1.0f;
  int bx = blockIdx.x * 32;  // C dim
  int by = blockIdx.y * 32;  // R dim
  int tx = threadIdx.x, ty = threadIdx.y;
  #pragma unroll
  for (int i = 0; i < 32; i += 8)
    tile[ty + i][tx] = in[(size_t)(by + ty + i) * C + bx + tx];
  __syncthreads();
  #pragma unroll
  for (int i = 0; i < 32; i += 8)
    outb[(size_t)(bx + ty + i) * R + by + tx] = f2bf(tile[tx][ty + i] * scale);
}

// ------------------------------------------------- v -> vT (bf16->bf16) ----
__global__ void vtrans(const unsigned short* __restrict__ v, unsigned short* __restrict__ vT) {
  __shared__ unsigned short tile[32][33];
  int bh = blockIdx.z, b = bh / 12, h = bh % 12;
  int s0 = blockIdx.x * 32, e0 = blockIdx.y * 32;
  int tx = threadIdx.x, ty = threadIdx.y;
  #pragma unroll
  for (int i = 0; i < 32; i += 8)
    tile[ty + i][tx] = v[(size_t)(b * 2048 + s0 + ty + i) * 768 + h * 64 + e0 + tx];
  __syncthreads();
  #pragma unroll
  for (int i = 0; i < 32; i += 8)
    vT[(size_t)((b * 12 + h) * 64 + e0 + ty + i) * 2048 + s0 + tx] = tile[tx][ty + i];
}

// ------------------------------------------------------------------ GEMM ---
// C[M,N] = A[M,K] @ Bt[N,K]^T ; epilogue by EPI bits:
//   1 = +bias[col], 2 = relu, 4 = +resid (fp32), 8 = store fp32 Cf,
//   16 = store bf16 Cb, 32 = QKV split bf16 store
template <int EPI>
__global__ void gemm_bf16(const unsigned short* __restrict__ A,
                          const unsigned short* __restrict__ Bt,
                          const float* __restrict__ bias,
                          const float* __restrict__ resid,
                          float* __restrict__ Cf,
                          unsigned short* __restrict__ Cb,
                          int M, int N, int K, int gx, size_t segN) {
  __shared__ unsigned short Alds[128 * 32];
  __shared__ unsigned short Blds[128 * 32];
  const int tid = threadIdx.x;
  const int lane = tid & 63;
  const int w = tid >> 6;
  const int wm = w & 1, wn = w >> 1;             // 2x2 wave grid
  const int wg = xcd_swz(blockIdx.x, gridDim.x);
  const int bm = (wg % gx) * 128, bn = (wg / gx) * 128;

  f32x4 acc[4][4] = {};

  const int r0 = tid >> 2;
  const int c0 = (tid & 3) * 8;

  for (int k0 = 0; k0 < K; k0 += 32) {
    __syncthreads();
    #pragma unroll
    for (int i = 0; i < 2; ++i) {
      int row = r0 + i * 64;
      gload16(&A[(size_t)(bm + row) * K + k0 + c0], &Alds[row * 32 + c0]);
      gload16(&Bt[(size_t)(bn + row) * K + k0 + c0], &Blds[row * 32 + c0]);
    }
    __syncthreads();
    bf16x8 af[4], bf[4];
    #pragma unroll
    for (int m = 0; m < 4; ++m)
      af[m] = *(const bf16x8*)&Alds[(wm * 64 + m * 16 + (lane & 15)) * 32 + (lane >> 4) * 8];
    #pragma unroll
    for (int n = 0; n < 4; ++n)
      bf[n] = *(const bf16x8*)&Blds[(wn * 64 + n * 16 + (lane & 15)) * 32 + (lane >> 4) * 8];
    #pragma unroll
    for (int m = 0; m < 4; ++m)
      #pragma unroll
      for (int n = 0; n < 4; ++n)
        acc[m][n] = __builtin_amdgcn_mfma_f32_16x16x32_bf16(af[m], bf[n], acc[m][n], 0, 0, 0);
  }

  const int crow0 = bm + wm * 64 + (lane >> 4) * 4;
  const int ccol0 = bn + wn * 64 + (lane & 15);
  const int seg = bn / 768;
  const int lcol0 = (bn % 768) + wn * 64 + (lane & 15);
  #pragma unroll
  for (int m = 0; m < 4; ++m) {
    #pragma unroll
    for (int n = 0; n < 4; ++n) {
      int col = ccol0 + n * 16;
      #pragma unroll
      for (int r = 0; r < 4; ++r) {
        int row = crow0 + m * 16 + r;
        float v = acc[m][n][r];
        if constexpr (EPI & 1) v += bias[col];
        if constexpr (EPI & 4) v += resid[(size_t)row * N + col];
        if constexpr (EPI & 2) v = fmaxf(v, 0.f);
        if constexpr (EPI & 8) Cf[(size_t)row * N + col] = v;
        if constexpr (EPI & 16) Cb[(size_t)row * N + col] = f2bf(v);
        if constexpr (EPI & 32)
          Cb[(size_t)seg * segN + (size_t)row * 768 + lcol0 + n * 16] = f2bf(v);
      }
    }
  }
}

// ------------------------------------------------------------- attention ---
// Swapped-QK^T causal flash attention, paired q-blocks.
// grid.x = 768 (16 pairs * 48 bh), XCD swizzled. 4 waves x 16 q-rows.
// q pre-scaled by 0.125*log2(e) -> softmax in exp2 domain.
// S-layout (D of mfma(K,Q)): q = lane&15, kv = kv0+n*16+(lane>>4)*4+r.
// O-layout (D of mfma(P,V)): q = (lane>>4)*4+r, e = n*16+lane&15.
__global__ void attn_fwd(const unsigned short* __restrict__ q,
                         const unsigned short* __restrict__ k,
                         const unsigned short* __restrict__ vT,
                         unsigned short* __restrict__ z) {
  __shared__ unsigned short Klds[2 * 2 * 64 * 32];  // [buf][hs-plane][kv row][32]
  __shared__ unsigned short Vlds[2 * 2 * 64 * 32];  // [buf][kv-plane][e row][32]
  __shared__ unsigned short Plds[4 * 16 * 72];      // per-wave [q row][72] padded

  const int wgid = xcd_swz(blockIdx.x, gridDim.x);
  const int pi = wgid & 15;
  const int bh = wgid >> 4;
  const int b = bh / 12, h = bh % 12;
  const int tid = threadIdx.x, lane = tid & 63, w = tid >> 6;
  const int q16 = lane & 15;          // q-col for S/P, e-col for V/O
  const int qt  = lane >> 4;          // quarter
  const int rdc = ((qt ^ (lane & 3)) * 8);  // swizzled K/V read chunk (shorts)

  const int srow = tid >> 2;                         // staging row
  const int sdc  = (tid & 3) * 8;                    // linear LDS dest chunk
  const int sgc  = (((tid & 3) ^ (srow & 3)) * 8);   // swizzled global src chunk
  const size_t kbase = (size_t)(b * 2048) * 768 + h * 64;
  const size_t vbase = (size_t)((b * 12 + h) * 64) * 2048;
  unsigned short* Pw = &Plds[w * 16 * 72];

  #pragma unroll 1
  for (int seg = 0; seg < 2; ++seg) {
    const int qb = seg == 0 ? pi : 31 - pi;
    const int q0 = qb * 64;
    const int nt = qb + 1;

    // Q fragments (B-frag: col=q16, k=qt*8)
    const int qrow = q0 + w * 16 + q16;
    const size_t qoff = (size_t)(b * 2048 + qrow) * 768 + h * 64 + qt * 8;
    bf16x8 qf0 = *(const bf16x8*)&q[qoff];
    bf16x8 qf1 = *(const bf16x8*)&q[qoff + 32];

    f32x4 accO[4] = {};
    float mrow = -3.0e38f, lrow = 0.f;

    // prologue: stage tile 0 into buf 0 (swizzled source, linear dest)
    #pragma unroll
    for (int i = 0; i < 2; ++i) {
      gload16(&k[kbase + (size_t)srow * 768 + i * 32 + sgc],
              &Klds[i * 2048 + srow * 32 + sdc]);
      gload16(&vT[vbase + (size_t)srow * 2048 + i * 32 + sgc],
              &Vlds[i * 2048 + srow * 32 + sdc]);
    }
    __syncthreads();

    int buf = 0;
    for (int t = 0; t < nt; ++t) {
      if (t + 1 < nt) {   // issue next tile's stage (overlaps compute)
        const int kv1 = (t + 1) * 64;
        const int bo = (buf ^ 1) * 4096;
        #pragma unroll
        for (int i = 0; i < 2; ++i) {
          gload16(&k[kbase + (size_t)(kv1 + srow) * 768 + i * 32 + sgc],
                  &Klds[bo + i * 2048 + srow * 32 + sdc]);
          gload16(&vT[vbase + (size_t)srow * 2048 + kv1 + i * 32 + sgc],
                  &Vlds[bo + i * 2048 + srow * 32 + sdc]);
        }
      }

      const int kv0 = t * 64;
      const int kb_ = buf * 4096;

      // S = K Q^T (swapped): s[n][r] is (q=q16, kv=kv0+n*16+qt*4+r)
      f32x4 s[4];
      #pragma unroll
      for (int n = 0; n < 4; ++n) {
        bf16x8 kf0 = *(const bf16x8*)&Klds[kb_ + 0 * 2048 + (n * 16 + q16) * 32 + rdc];
        bf16x8 kf1 = *(const bf16x8*)&Klds[kb_ + 1 * 2048 + (n * 16 + q16) * 32 + rdc];
        f32x4 acc0 = {};
        acc0 = __builtin_amdgcn_mfma_f32_16x16x32_bf16(kf0, qf0, acc0, 0, 0, 0);
        s[n] = __builtin_amdgcn_mfma_f32_16x16x32_bf16(kf1, qf1, acc0, 0, 0, 0);
      }

      if (t == nt - 1) {  // diagonal tile: causal mask
        const int rowg = q0 + w * 16 + q16;      // q
        #pragma unroll
        for (int n = 0; n < 4; ++n)
          #pragma unroll
          for (int r = 0; r < 4; ++r)
            if (kv0 + n * 16 + qt * 4 + r > rowg) s[n][r] = -3.0e38f;
      }

      // row max: 15 in-lane fmax + 2 shuffles
      float pm = s[0][0];
      #pragma unroll
      for (int n = 0; n < 4; ++n)
        #pragma unroll
        for (int r = 0; r < 4; ++r) pm = fmaxf(pm, s[n][r]);
      pm = fmaxf(pm, __shfl_xor(pm, 16));
      pm = fmaxf(pm, __shfl_xor(pm, 32));

      // defer-max (T13): rescale only when max grew past threshold
      if (__any(pm > mrow + 8.f)) {
        float mnew = fmaxf(mrow, pm);
        float sc = exp2f(mrow - mnew);
        mrow = mnew;
        lrow *= sc;
        int isc = __float_as_int(sc);
        #pragma unroll
        for (int r = 0; r < 4; ++r) {
          float scr = __int_as_float(__builtin_amdgcn_ds_bpermute((qt * 4 + r) * 4, isc));
          #pragma unroll
          for (int n = 0; n < 4; ++n) accO[n][r] *= scr;
        }
      }

      // p = exp2(s - m), row sum: 16 in-lane adds + 2 shuffles
      float psum = 0.f;
      #pragma unroll
      for (int n = 0; n < 4; ++n)
        #pragma unroll
        for (int r = 0; r < 4; ++r) { s[n][r] = exp2f(s[n][r] - mrow); psum += s[n][r]; }
      psum += __shfl_xor(psum, 16);
      psum += __shfl_xor(psum, 32);
      lrow += psum;

      // pack P -> per-wave padded LDS: row q16, col kv-local (stride 72)
      #pragma unroll
      for (int n = 0; n < 4; ++n) {
        unsigned int lo, hi;
        asm("v_cvt_pk_bf16_f32 %0, %1, %2" : "=v"(lo) : "v"(s[n][0]), "v"(s[n][1]));
        asm("v_cvt_pk_bf16_f32 %0, %1, %2" : "=v"(hi) : "v"(s[n][2]), "v"(s[n][3]));
        uint2 pk; pk.x = lo; pk.y = hi;
        *(uint2*)&Pw[q16 * 72 + n * 16 + qt * 4] = pk;
      }

      // O += P V  (A-frag: row=q16, k=qt*8; B-frag: col=q16(e), k=qt*8(kv))
      #pragma unroll
      for (int kk = 0; kk < 2; ++kk) {
        bf16x8 pf = *(const bf16x8*)&Pw[q16 * 72 + kk * 32 + qt * 8];
        #pragma unroll
        for (int n = 0; n < 4; ++n) {
          bf16x8 vf = *(const bf16x8*)&Vlds[kb_ + kk * 2048 + (n * 16 + q16) * 32 + rdc];
          accO[n] = __builtin_amdgcn_mfma_f32_16x16x32_bf16(pf, vf, accO[n], 0, 0, 0);
        }
      }

      __syncthreads();   // drains stage of t+1 + protects buf reuse
      buf ^= 1;
    }

    // epilogue: divide by l (bpermute l into O row layout) and store
    #pragma unroll
    for (int r = 0; r < 4; ++r) {
      float lr = __int_as_float(__builtin_amdgcn_ds_bpermute((qt * 4 + r) * 4,
                                                             __float_as_int(lrow)));
      float linv = 1.0f / lr;
      int rowg = q0 + w * 16 + qt * 4 + r;
      #pragma unroll
      for (int n = 0; n < 4; ++n)
        z[(size_t)(b * 2048 + rowg) * 768 + h * 64 + n * 16 + q16]
            = f2bf(accO[n][r] * linv);
    }
  }
}

// ---------------------------------------------------------------- launch ---
extern "C" void kernel_launch(void* const* d_in, const int* in_sizes, int n_in,
                              void* d_out, int out_size, void* d_ws, size_t ws_size,
                              hipStream_t stream) {
  const float* x  = (const float*)d_in[0];
  const float* Wq = (const float*)d_in[1];
  const float* Wk = (const float*)d_in[2];
  const float* Wv = (const float*)d_in[3];
  const float* Wo = (const float*)d_in[4];
  const float* bo = (const float*)d_in[5];
  const float* W1 = (const float*)d_in[6];
  const float* b1 = (const float*)d_in[7];
  const float* W2 = (const float*)d_in[8];
  const float* b2 = (const float*)d_in[9];
  float* out = (float*)d_out;

  const int B = 4, S = 2048, D = 768, H = 12, hs = 64, F = 3072;
  const int M = B * S;                 // 8192
  const size_t MD = (size_t)M * D;     // 6291456

  unsigned short* xb   = (unsigned short*)d_ws;
  unsigned short* qb   = xb + MD;
  unsigned short* kb   = qb + MD;
  unsigned short* vb   = kb + MD;
  unsigned short* hbuf = xb;           // [M, F] bf16, reuse
  unsigned short* vT   = vb + MD;
  unsigned short* zb   = vT + MD;
  float*          z2f  = (float*)(zb + MD);
  unsigned short* z2b  = (unsigned short*)(z2f + MD);
  unsigned short* wqkvT= z2b + MD;     // [2304][768] bf16
  unsigned short* woT  = wqkvT + 3 * (size_t)D * D;
  unsigned short* w1T  = woT + (size_t)D * D;
  unsigned short* w2T  = w1T + (size_t)D * F;

  dim3 tb(32, 8);

  castx<<<dim3((int)(MD / 4 / 256)), 256, 0, stream>>>(x, xb, (int)MD);

  // q scale folds 1/sqrt(64) AND log2(e): softmax runs in exp2 domain
  const float QS = 0.125f * 1.4426950408889634f;
  tcast3<<<dim3(hs / 32, D / 32, 3 * H), tb, 0, stream>>>(Wq, Wk, Wv, wqkvT, QS);
  tcast<<<dim3(D / 32, D / 32, 1), tb, 0, stream>>>(Wo, woT, D, D, 1.0f);
  tcast<<<dim3(F / 32, D / 32, 1), tb, 0, stream>>>(W1, w1T, D, F, 1.0f);
  tcast<<<dim3(D / 32, F / 32, 1), tb, 0, stream>>>(W2, w2T, F, D, 1.0f);

  // fused QKV: [M,768] @ [768,2304] -> q,k,v bf16 (split store)
  {
    int gx = M / 128, gy = 3 * D / 128;
    gemm_bf16<32><<<dim3(gx * gy), 256, 0, stream>>>(xb, wqkvT, nullptr, nullptr,
                                                     nullptr, qb, M, 3 * D, D, gx, MD);
  }

  vtrans<<<dim3(S / 32, hs / 32, B * H), tb, 0, stream>>>(vb, vT);

  attn_fwd<<<dim3((S / 128) * B * H), 256, 0, stream>>>(qb, kb, vT, zb);

  // z @ Wo + bo + x -> z2 (fp32 + bf16)
  {
    int gx = M / 128, gy = D / 128;
    gemm_bf16<1 | 4 | 8 | 16><<<dim3(gx * gy), 256, 0, stream>>>(zb, woT, bo, x,
                                                                 z2f, z2b, M, D, D, gx, 0);
  }
  // relu(z2 @ W1 + b1) -> h (bf16)
  {
    int gx = M / 128, gy = F / 128;
    gemm_bf16<1 | 2 | 16><<<dim3(gx * gy), 256, 0, stream>>>(z2b, w1T, b1, nullptr,
                                                             nullptr, hbuf, M, F, D, gx, 0);
  }
  // h @ W2 + b2 + z2 -> out (fp32)
  {
    int gx = M / 128, gy = D / 128;
    gemm_bf16<1 | 4 | 8><<<dim3(gx * gy), 256, 0, stream>>>(hbuf, w2T, b2, z2f,
                                                            out, nullptr, M, D, F, gx, 0);
  }
}

// Round 4
// 288.599 us; speedup vs baseline: 1.4474x; 1.0688x over previous
//
#include <hip/hip_runtime.h>

// ---------------------------------------------------------------------------
// TransformerBlock on MI355X (gfx950): bf16 MFMA pipeline
//   B=4 S=2048 D=768 H=12 hs=64 F=3072, M=B*S=8192
// Round 4: GEMM L2 supertiling (8 bm-rows per XCD chunk) + 2-phase
//          overlapped K-loop with double-buffered LDS (1 barrier/step).
//          Attention unchanged from R3 (swapped QK^T, lane-local softmax).
// ---------------------------------------------------------------------------

typedef __attribute__((ext_vector_type(4))) float f32x4;
typedef __attribute__((ext_vector_type(8))) short bf16x8;   // 8 bf16 in 4 VGPRs
typedef __attribute__((ext_vector_type(4))) unsigned short u16x4;

#define GLB_AS __attribute__((address_space(1)))
#define LDS_AS __attribute__((address_space(3)))

__device__ __forceinline__ unsigned short f2bf(float f) {
  unsigned int u = __float_as_uint(f);
  u = (u + 0x7FFFu + ((u >> 16) & 1u)) >> 16;   // RNE
  return (unsigned short)u;
}

__device__ __forceinline__ void gload16(const void* g, void* l) {
  __builtin_amdgcn_global_load_lds((const GLB_AS unsigned int*)g,
                                   (LDS_AS unsigned int*)l, 16, 0, 0);
}

// bijective XCD swizzle (m204): contiguous chunk of wg-ids per XCD
__device__ __forceinline__ int xcd_swz(int orig, int nwg) {
  int q = nwg >> 3, r = nwg & 7;
  int xcd = orig & 7, rest = orig >> 3;
  return (xcd < r ? xcd * (q + 1) : r * (q + 1) + (xcd - r) * q) + rest;
}

// ---------------------------------------------------------------- cast x ---
__global__ void castx(const float* __restrict__ in, unsigned short* __restrict__ out, int n) {
  int i = (blockIdx.x * 256 + threadIdx.x) * 4;
  if (i < n) {
    float4 f = *(const float4*)&in[i];
    u16x4 o;
    o[0] = f2bf(f.x); o[1] = f2bf(f.y); o[2] = f2bf(f.z); o[3] = f2bf(f.w);
    *(u16x4*)&out[i] = o;
  }
}

// ---------------------------------------------- weight transpose + cast ----
__global__ void tcast(const float* __restrict__ in, unsigned short* __restrict__ out,
                      int R, int C, float scale) {
  __shared__ float tile[32][33];
  const float* inb = in + (size_t)blockIdx.z * R * C;
  unsigned short* outb = out + (size_t)blockIdx.z * R * C;
  int bx = blockIdx.x * 32;  // C dim
  int by = blockIdx.y * 32;  // R dim
  int tx = threadIdx.x, ty = threadIdx.y;
  #pragma unroll
  for (int i = 0; i < 32; i += 8) {
    int r = by + ty + i, c = bx + tx;
    tile[ty + i][tx] = inb[(size_t)r * C + c];
  }
  __syncthreads();
  #pragma unroll
  for (int i = 0; i < 32; i += 8) {
    int c = bx + ty + i, r = by + tx;
    outb[(size_t)c * R + r] = f2bf(tile[tx][ty + i] * scale);
  }
}

// Wq/Wk/Wv transposes in one launch: z in [0,36), w=z/12 picks the matrix.
__global__ void tcast3(const float* __restrict__ Wq, const float* __restrict__ Wk,
                       const float* __restrict__ Wv, unsigned short* __restrict__ out,
                       float qscale) {
  __shared__ float tile[32][33];
  const int R = 768, C = 64;
  int z = blockIdx.z, wsel = z / 12, head = z % 12;
  const float* in = (wsel == 0 ? Wq : wsel == 1 ? Wk : Wv) + (size_t)head * R * C;
  unsigned short* outb = out + (size_t)wsel * R * R + (size_t)head * R * C;
  float scale = wsel == 0 ? qscale : 1.0f;
  int bx = blockIdx.x * 32;  // C dim
  int by = blockIdx.y * 32;  // R dim
  int tx = threadIdx.x, ty = threadIdx.y;
  #pragma unroll
  for (int i = 0; i < 32; i += 8)
    tile[ty + i][tx] = in[(size_t)(by + ty + i) * C + bx + tx];
  __syncthreads();
  #pragma unroll
  for (int i = 0; i < 32; i += 8)
    outb[(size_t)(bx + ty + i) * R + by + tx] = f2bf(tile[tx][ty + i] * scale);
}

// ------------------------------------------------- v -> vT (bf16->bf16) ----
__global__ void vtrans(const unsigned short* __restrict__ v, unsigned short* __restrict__ vT) {
  __shared__ unsigned short tile[32][33];
  int bh = blockIdx.z, b = bh / 12, h = bh % 12;
  int s0 = blockIdx.x * 32, e0 = blockIdx.y * 32;
  int tx = threadIdx.x, ty = threadIdx.y;
  #pragma unroll
  for (int i = 0; i < 32; i += 8)
    tile[ty + i][tx] = v[(size_t)(b * 2048 + s0 + ty + i) * 768 + h * 64 + e0 + tx];
  __syncthreads();
  #pragma unroll
  for (int i = 0; i < 32; i += 8)
    vT[(size_t)((b * 12 + h) * 64 + e0 + ty + i) * 2048 + s0 + tx] = tile[tx][ty + i];
}

// ------------------------------------------------------------------ GEMM ---
// C[M,N] = A[M,K] @ Bt[N,K]^T ; epilogue by EPI bits:
//   1 = +bias[col], 2 = relu, 4 = +resid (fp32), 8 = store fp32 Cf,
//   16 = store bf16 Cb, 32 = QKV split bf16 store
// Grid: flattened gx*gy, gx = M/128 = 64. Mapping: XCD-chunk (xcd_swz) then
// supertile decompose (8 bm-rows x all bn, bm fastest) -> per-XCD L2 working
// set = 8 A-panels (1.5 MB) + streaming B panels.
// K-loop: double-buffered LDS, stage(t+1) issued before compute(t),
// one barrier per K-step (T3-minimum 2-phase).
template <int EPI>
__global__ void gemm_bf16(const unsigned short* __restrict__ A,
                          const unsigned short* __restrict__ Bt,
                          const float* __restrict__ bias,
                          const float* __restrict__ resid,
                          float* __restrict__ Cf,
                          unsigned short* __restrict__ Cb,
                          int M, int N, int K, int gy, size_t segN) {
  __shared__ unsigned short Alds[2][128 * 32];
  __shared__ unsigned short Blds[2][128 * 32];
  const int tid = threadIdx.x;
  const int lane = tid & 63;
  const int w = tid >> 6;
  const int wm = w & 1, wn = w >> 1;             // 2x2 wave grid
  const int wg = xcd_swz(blockIdx.x, gridDim.x);
  // supertile: groups of 8 bm-rows x gy bn-cols, bm fastest within group
  const int gsz = 8 * gy;
  const int group = wg / gsz;
  const int rem = wg - group * gsz;
  const int bm = (group * 8 + (rem & 7)) * 128;
  const int bn = (rem >> 3) * 128;

  f32x4 acc[4][4] = {};

  const int r0 = tid >> 2;            // staging row
  const int c0 = (tid & 3) * 8;       // staging col (elements)

  // prologue: stage k0=0 into buf 0
  #pragma unroll
  for (int i = 0; i < 2; ++i) {
    int row = r0 + i * 64;
    gload16(&A[(size_t)(bm + row) * K + c0], &Alds[0][row * 32 + c0]);
    gload16(&Bt[(size_t)(bn + row) * K + c0], &Blds[0][row * 32 + c0]);
  }
  __syncthreads();

  int buf = 0;
  for (int k0 = 0; k0 < K; k0 += 32) {
    // issue next K-step's stage first (overlaps with ds_read + MFMA below)
    if (k0 + 32 < K) {
      #pragma unroll
      for (int i = 0; i < 2; ++i) {
        int row = r0 + i * 64;
        gload16(&A[(size_t)(bm + row) * K + k0 + 32 + c0], &Alds[buf ^ 1][row * 32 + c0]);
        gload16(&Bt[(size_t)(bn + row) * K + k0 + 32 + c0], &Blds[buf ^ 1][row * 32 + c0]);
      }
    }
    bf16x8 af[4], bf[4];
    #pragma unroll
    for (int m = 0; m < 4; ++m)
      af[m] = *(const bf16x8*)&Alds[buf][(wm * 64 + m * 16 + (lane & 15)) * 32 + (lane >> 4) * 8];
    #pragma unroll
    for (int n = 0; n < 4; ++n)
      bf[n] = *(const bf16x8*)&Blds[buf][(wn * 64 + n * 16 + (lane & 15)) * 32 + (lane >> 4) * 8];
    #pragma unroll
    for (int m = 0; m < 4; ++m)
      #pragma unroll
      for (int n = 0; n < 4; ++n)
        acc[m][n] = __builtin_amdgcn_mfma_f32_16x16x32_bf16(af[m], bf[n], acc[m][n], 0, 0, 0);
    __syncthreads();   // implicit vmcnt(0)+lgkmcnt(0): prefetch landed, buf reusable
    buf ^= 1;
  }

  const int crow0 = bm + wm * 64 + (lane >> 4) * 4;
  const int ccol0 = bn + wn * 64 + (lane & 15);
  const int seg = bn / 768;
  const int lcol0 = (bn % 768) + wn * 64 + (lane & 15);
  #pragma unroll
  for (int m = 0; m < 4; ++m) {
    #pragma unroll
    for (int n = 0; n < 4; ++n) {
      int col = ccol0 + n * 16;
      #pragma unroll
      for (int r = 0; r < 4; ++r) {
        int row = crow0 + m * 16 + r;
        float v = acc[m][n][r];
        if constexpr (EPI & 1) v += bias[col];
        if constexpr (EPI & 4) v += resid[(size_t)row * N + col];
        if constexpr (EPI & 2) v = fmaxf(v, 0.f);
        if constexpr (EPI & 8) Cf[(size_t)row * N + col] = v;
        if constexpr (EPI & 16) Cb[(size_t)row * N + col] = f2bf(v);
        if constexpr (EPI & 32)
          Cb[(size_t)seg * segN + (size_t)row * 768 + lcol0 + n * 16] = f2bf(v);
      }
    }
  }
}

// ------------------------------------------------------------- attention ---
// Swapped-QK^T causal flash attention, paired q-blocks (unchanged from R3).
__global__ void attn_fwd(const unsigned short* __restrict__ q,
                         const unsigned short* __restrict__ k,
                         const unsigned short* __restrict__ vT,
                         unsigned short* __restrict__ z) {
  __shared__ unsigned short Klds[2 * 2 * 64 * 32];  // [buf][hs-plane][kv row][32]
  __shared__ unsigned short Vlds[2 * 2 * 64 * 32];  // [buf][kv-plane][e row][32]
  __shared__ unsigned short Plds[4 * 16 * 72];      // per-wave [q row][72] padded

  const int wgid = xcd_swz(blockIdx.x, gridDim.x);
  const int pi = wgid & 15;
  const int bh = wgid >> 4;
  const int b = bh / 12, h = bh % 12;
  const int tid = threadIdx.x, lane = tid & 63, w = tid >> 6;
  const int q16 = lane & 15;
  const int qt  = lane >> 4;
  const int rdc = ((qt ^ (lane & 3)) * 8);  // swizzled K/V read chunk (shorts)

  const int srow = tid >> 2;
  const int sdc  = (tid & 3) * 8;
  const int sgc  = (((tid & 3) ^ (srow & 3)) * 8);
  const size_t kbase = (size_t)(b * 2048) * 768 + h * 64;
  const size_t vbase = (size_t)((b * 12 + h) * 64) * 2048;
  unsigned short* Pw = &Plds[w * 16 * 72];

  #pragma unroll 1
  for (int seg = 0; seg < 2; ++seg) {
    const int qb = seg == 0 ? pi : 31 - pi;
    const int q0 = qb * 64;
    const int nt = qb + 1;

    const int qrow = q0 + w * 16 + q16;
    const size_t qoff = (size_t)(b * 2048 + qrow) * 768 + h * 64 + qt * 8;
    bf16x8 qf0 = *(const bf16x8*)&q[qoff];
    bf16x8 qf1 = *(const bf16x8*)&q[qoff + 32];

    f32x4 accO[4] = {};
    float mrow = -3.0e38f, lrow = 0.f;

    #pragma unroll
    for (int i = 0; i < 2; ++i) {
      gload16(&k[kbase + (size_t)srow * 768 + i * 32 + sgc],
              &Klds[i * 2048 + srow * 32 + sdc]);
      gload16(&vT[vbase + (size_t)srow * 2048 + i * 32 + sgc],
              &Vlds[i * 2048 + srow * 32 + sdc]);
    }
    __syncthreads();

    int buf = 0;
    for (int t = 0; t < nt; ++t) {
      if (t + 1 < nt) {
        const int kv1 = (t + 1) * 64;
        const int bo = (buf ^ 1) * 4096;
        #pragma unroll
        for (int i = 0; i < 2; ++i) {
          gload16(&k[kbase + (size_t)(kv1 + srow) * 768 + i * 32 + sgc],
                  &Klds[bo + i * 2048 + srow * 32 + sdc]);
          gload16(&vT[vbase + (size_t)srow * 2048 + kv1 + i * 32 + sgc],
                  &Vlds[bo + i * 2048 + srow * 32 + sdc]);
        }
      }

      const int kv0 = t * 64;
      const int kb_ = buf * 4096;

      f32x4 s[4];
      #pragma unroll
      for (int n = 0; n < 4; ++n) {
        bf16x8 kf0 = *(const bf16x8*)&Klds[kb_ + 0 * 2048 + (n * 16 + q16) * 32 + rdc];
        bf16x8 kf1 = *(const bf16x8*)&Klds[kb_ + 1 * 2048 + (n * 16 + q16) * 32 + rdc];
        f32x4 acc0 = {};
        acc0 = __builtin_amdgcn_mfma_f32_16x16x32_bf16(kf0, qf0, acc0, 0, 0, 0);
        s[n] = __builtin_amdgcn_mfma_f32_16x16x32_bf16(kf1, qf1, acc0, 0, 0, 0);
      }

      if (t == nt - 1) {
        const int rowg = q0 + w * 16 + q16;
        #pragma unroll
        for (int n = 0; n < 4; ++n)
          #pragma unroll
          for (int r = 0; r < 4; ++r)
            if (kv0 + n * 16 + qt * 4 + r > rowg) s[n][r] = -3.0e38f;
      }

      float pm = s[0][0];
      #pragma unroll
      for (int n = 0; n < 4; ++n)
        #pragma unroll
        for (int r = 0; r < 4; ++r) pm = fmaxf(pm, s[n][r]);
      pm = fmaxf(pm, __shfl_xor(pm, 16));
      pm = fmaxf(pm, __shfl_xor(pm, 32));

      if (__any(pm > mrow + 8.f)) {
        float mnew = fmaxf(mrow, pm);
        float sc = exp2f(mrow - mnew);
        mrow = mnew;
        lrow *= sc;
        int isc = __float_as_int(sc);
        #pragma unroll
        for (int r = 0; r < 4; ++r) {
          float scr = __int_as_float(__builtin_amdgcn_ds_bpermute((qt * 4 + r) * 4, isc));
          #pragma unroll
          for (int n = 0; n < 4; ++n) accO[n][r] *= scr;
        }
      }

      float psum = 0.f;
      #pragma unroll
      for (int n = 0; n < 4; ++n)
        #pragma unroll
        for (int r = 0; r < 4; ++r) { s[n][r] = exp2f(s[n][r] - mrow); psum += s[n][r]; }
      psum += __shfl_xor(psum, 16);
      psum += __shfl_xor(psum, 32);
      lrow += psum;

      #pragma unroll
      for (int n = 0; n < 4; ++n) {
        unsigned int lo, hi;
        asm("v_cvt_pk_bf16_f32 %0, %1, %2" : "=v"(lo) : "v"(s[n][0]), "v"(s[n][1]));
        asm("v_cvt_pk_bf16_f32 %0, %1, %2" : "=v"(hi) : "v"(s[n][2]), "v"(s[n][3]));
        uint2 pk; pk.x = lo; pk.y = hi;
        *(uint2*)&Pw[q16 * 72 + n * 16 + qt * 4] = pk;
      }

      #pragma unroll
      for (int kk = 0; kk < 2; ++kk) {
        bf16x8 pf = *(const bf16x8*)&Pw[q16 * 72 + kk * 32 + qt * 8];
        #pragma unroll
        for (int n = 0; n < 4; ++n) {
          bf16x8 vf = *(const bf16x8*)&Vlds[kb_ + kk * 2048 + (n * 16 + q16) * 32 + rdc];
          accO[n] = __builtin_amdgcn_mfma_f32_16x16x32_bf16(pf, vf, accO[n], 0, 0, 0);
        }
      }

      __syncthreads();
      buf ^= 1;
    }

    #pragma unroll
    for (int r = 0; r < 4; ++r) {
      float lr = __int_as_float(__builtin_amdgcn_ds_bpermute((qt * 4 + r) * 4,
                                                             __float_as_int(lrow)));
      float linv = 1.0f / lr;
      int rowg = q0 + w * 16 + qt * 4 + r;
      #pragma unroll
      for (int n = 0; n < 4; ++n)
        z[(size_t)(b * 2048 + rowg) * 768 + h * 64 + n * 16 + q16]
            = f2bf(accO[n][r] * linv);
    }
  }
}

// ---------------------------------------------------------------- launch ---
extern "C" void kernel_launch(void* const* d_in, const int* in_sizes, int n_in,
                              void* d_out, int out_size, void* d_ws, size_t ws_size,
                              hipStream_t stream) {
  const float* x  = (const float*)d_in[0];
  const float* Wq = (const float*)d_in[1];
  const float* Wk = (const float*)d_in[2];
  const float* Wv = (const float*)d_in[3];
  const float* Wo = (const float*)d_in[4];
  const float* bo = (const float*)d_in[5];
  const float* W1 = (const float*)d_in[6];
  const float* b1 = (const float*)d_in[7];
  const float* W2 = (const float*)d_in[8];
  const float* b2 = (const float*)d_in[9];
  float* out = (float*)d_out;

  const int B = 4, S = 2048, D = 768, H = 12, hs = 64, F = 3072;
  const int M = B * S;                 // 8192
  const size_t MD = (size_t)M * D;     // 6291456

  unsigned short* xb   = (unsigned short*)d_ws;
  unsigned short* qb   = xb + MD;
  unsigned short* kb   = qb + MD;
  unsigned short* vb   = kb + MD;
  unsigned short* hbuf = xb;           // [M, F] bf16, reuse
  unsigned short* vT   = vb + MD;
  unsigned short* zb   = vT + MD;
  float*          z2f  = (float*)(zb + MD);
  unsigned short* z2b  = (unsigned short*)(z2f + MD);
  unsigned short* wqkvT= z2b + MD;     // [2304][768] bf16
  unsigned short* woT  = wqkvT + 3 * (size_t)D * D;
  unsigned short* w1T  = woT + (size_t)D * D;
  unsigned short* w2T  = w1T + (size_t)D * F;

  dim3 tb(32, 8);

  castx<<<dim3((int)(MD / 4 / 256)), 256, 0, stream>>>(x, xb, (int)MD);

  // q scale folds 1/sqrt(64) AND log2(e): softmax runs in exp2 domain
  const float QS = 0.125f * 1.4426950408889634f;
  tcast3<<<dim3(hs / 32, D / 32, 3 * H), tb, 0, stream>>>(Wq, Wk, Wv, wqkvT, QS);
  tcast<<<dim3(D / 32, D / 32, 1), tb, 0, stream>>>(Wo, woT, D, D, 1.0f);
  tcast<<<dim3(F / 32, D / 32, 1), tb, 0, stream>>>(W1, w1T, D, F, 1.0f);
  tcast<<<dim3(D / 32, F / 32, 1), tb, 0, stream>>>(W2, w2T, F, D, 1.0f);

  // fused QKV: [M,768] @ [768,2304] -> q,k,v bf16 (split store)
  {
    int gy = 3 * D / 128;  // 18
    gemm_bf16<32><<<dim3(64 * gy), 256, 0, stream>>>(xb, wqkvT, nullptr, nullptr,
                                                     nullptr, qb, M, 3 * D, D, gy, MD);
  }

  vtrans<<<dim3(S / 32, hs / 32, B * H), tb, 0, stream>>>(vb, vT);

  attn_fwd<<<dim3((S / 128) * B * H), 256, 0, stream>>>(qb, kb, vT, zb);

  // z @ Wo + bo + x -> z2 (fp32 + bf16)
  {
    int gy = D / 128;  // 6
    gemm_bf16<1 | 4 | 8 | 16><<<dim3(64 * gy), 256, 0, stream>>>(zb, woT, bo, x,
                                                                 z2f, z2b, M, D, D, gy, 0);
  }
  // relu(z2 @ W1 + b1) -> h (bf16)
  {
    int gy = F / 128;  // 24
    gemm_bf16<1 | 2 | 16><<<dim3(64 * gy), 256, 0, stream>>>(z2b, w1T, b1, nullptr,
                                                             nullptr, hbuf, M, F, D, gy, 0);
  }
  // h @ W2 + b2 + z2 -> out (fp32)
  {
    int gy = D / 128;  // 6
    gemm_bf16<1 | 4 | 8><<<dim3(64 * gy), 256, 0, stream>>>(hbuf, w2T, b2, z2f,
                                                            out, nullptr, M, D, F, gy, 0);
  }
}